// Round 1
// baseline (1277.813 us; speedup 1.0000x reference)
//
#include <hip/hip_runtime.h>

#define N_NODES 100000
#define N_EDGES 3200000
#define IN_DIM 256
#define HIDDEN 128
#define OUT_DIM 64

// ---------------- CSR build ----------------

__global__ void zero_kernel(int* __restrict__ p, int n) {
    int i = blockIdx.x * blockDim.x + threadIdx.x;
    if (i < n) p[i] = 0;
}

__global__ void hist_kernel(const int* __restrict__ dst, int* __restrict__ deg, int n) {
    int i = blockIdx.x * blockDim.x + threadIdx.x;
    if (i < n) atomicAdd(&deg[dst[i]], 1);
}

// chunk = 1024 elements per block (256 thr x 4)
__global__ void scan_reduce(const int* __restrict__ deg, int* __restrict__ partial, int n) {
    __shared__ int s[256];
    int b = blockIdx.x, tid = threadIdx.x;
    int base = b * 1024 + tid * 4;
    int sum = 0;
#pragma unroll
    for (int i = 0; i < 4; i++) {
        int idx = base + i;
        if (idx < n) sum += deg[idx];
    }
    s[tid] = sum;
    __syncthreads();
    for (int off = 128; off > 0; off >>= 1) {
        if (tid < off) s[tid] += s[tid + off];
        __syncthreads();
    }
    if (tid == 0) partial[b] = s[0];
}

__global__ void scan_partials(int* partial, int nb) {
    __shared__ int s[128];
    int tid = threadIdx.x;
    int v = (tid < nb) ? partial[tid] : 0;
    s[tid] = v;
    __syncthreads();
    for (int off = 1; off < 128; off <<= 1) {
        int t = 0;
        if (tid >= off) t = s[tid - off];
        __syncthreads();
        if (tid >= off) s[tid] += t;
        __syncthreads();
    }
    if (tid < nb) partial[tid] = s[tid] - v;  // exclusive prefix
}

__global__ void scan_final(const int* __restrict__ deg, const int* __restrict__ partial,
                           int* __restrict__ row_ptr, int n, int total) {
    __shared__ int s[256];
    int b = blockIdx.x, tid = threadIdx.x;
    int base = b * 1024 + tid * 4;
    int v[4];
#pragma unroll
    for (int i = 0; i < 4; i++) {
        int idx = base + i;
        v[i] = (idx < n) ? deg[idx] : 0;
    }
    int tsum = v[0] + v[1] + v[2] + v[3];
    s[tid] = tsum;
    __syncthreads();
    for (int off = 1; off < 256; off <<= 1) {
        int t = 0;
        if (tid >= off) t = s[tid - off];
        __syncthreads();
        if (tid >= off) s[tid] += t;
        __syncthreads();
    }
    int run = partial[b] + (s[tid] - tsum);
#pragma unroll
    for (int i = 0; i < 4; i++) {
        int idx = base + i;
        if (idx < n) row_ptr[idx] = run;
        run += v[i];
    }
    if (b == 0 && tid == 0) row_ptr[n] = total;
}

__global__ void copy_kernel(const int* __restrict__ src, int* __restrict__ dst, int n) {
    int i = blockIdx.x * blockDim.x + threadIdx.x;
    if (i < n) dst[i] = src[i];
}

__global__ void scatter_kernel(const int* __restrict__ esrc, const int* __restrict__ edst,
                               const float* __restrict__ evals, int* __restrict__ cursor,
                               int* __restrict__ csr_col, float* __restrict__ csr_val, int n) {
    int i = blockIdx.x * blockDim.x + threadIdx.x;
    if (i < n) {
        int d = edst[i];
        int p = atomicAdd(&cursor[d], 1);
        csr_col[p] = esrc[i];
        csr_val[p] = evals[i];
    }
}

// ---------------- dense GEMM (fp32 vector ALU; no fp32 MFMA on CDNA4) ----------------
// C[M,BN] = A[M,K] @ B[K,BN], BM=64, BK=32, 256 threads, 4xTN micro-tile (TN = BN/16)

template <int K, int BN, int TN>
__launch_bounds__(256)
__global__ void gemm_kernel(const float* __restrict__ A, const float* __restrict__ B,
                            float* __restrict__ C, int M) {
    constexpr int BM = 64, BK = 32;
    __shared__ float As[BK][BM + 1];  // +1 pad: conflict-free transpose store
    __shared__ float Bs[BK][BN];
    int tid = threadIdx.x;
    int tm = tid >> 4, tn = tid & 15;  // 16x16 thread grid
    int rowBase = blockIdx.x * BM;
    float acc[4][TN];
#pragma unroll
    for (int r = 0; r < 4; r++)
#pragma unroll
        for (int c = 0; c < TN; c++) acc[r][c] = 0.f;

    for (int k0 = 0; k0 < K; k0 += BK) {
        // A tile: 64x32, 8 elems/thread, coalesced along k
#pragma unroll
        for (int i = 0; i < 8; i++) {
            int idx = tid + i * 256;
            int m = idx >> 5, kk = idx & 31;
            int row = rowBase + m;
            As[kk][m] = (row < M) ? A[(size_t)row * K + k0 + kk] : 0.f;
        }
        // B tile: 32xBN, coalesced
#pragma unroll
        for (int i = 0; i < (BK * BN) / 256; i++) {
            int idx = tid + i * 256;
            int kk = idx / BN, nn = idx % BN;
            Bs[kk][nn] = B[(size_t)(k0 + kk) * BN + nn];
        }
        __syncthreads();
#pragma unroll
        for (int kk = 0; kk < BK; kk++) {
            float a[4], bb[TN];
#pragma unroll
            for (int r = 0; r < 4; r++) a[r] = As[kk][tm * 4 + r];
#pragma unroll
            for (int c = 0; c < TN; c++) bb[c] = Bs[kk][tn * TN + c];
#pragma unroll
            for (int r = 0; r < 4; r++)
#pragma unroll
                for (int c = 0; c < TN; c++) acc[r][c] += a[r] * bb[c];
        }
        __syncthreads();
    }
#pragma unroll
    for (int r = 0; r < 4; r++) {
        int row = rowBase + tm * 4 + r;
        if (row < M) {
#pragma unroll
            for (int c = 0; c < TN; c++) C[(size_t)row * BN + tn * TN + c] = acc[r][c];
        }
    }
}

// ---------------- SpMM: one wave per dst row, CSR, no atomics ----------------

template <int D, bool RELU>
__launch_bounds__(256)
__global__ void spmm_kernel(const float* __restrict__ feat, const int* __restrict__ csr_col,
                            const float* __restrict__ csr_val, const int* __restrict__ row_ptr,
                            float* __restrict__ out, int n) {
    int wid = threadIdx.x >> 6;
    int lane = threadIdx.x & 63;
    int row = blockIdx.x * 4 + wid;
    if (row >= n) return;
    int s = row_ptr[row], e = row_ptr[row + 1];
    if (D == 128) {
        float ax = 0.f, ay = 0.f;
        for (int i = s; i < e; i++) {
            int c = csr_col[i];
            float v = csr_val[i];
            const float2 xv = *reinterpret_cast<const float2*>(feat + (size_t)c * 128 + lane * 2);
            ax += v * xv.x;
            ay += v * xv.y;
        }
        if (RELU) {
            ax = ax > 0.f ? ax : 0.f;
            ay = ay > 0.f ? ay : 0.f;
        }
        *reinterpret_cast<float2*>(out + (size_t)row * 128 + lane * 2) = make_float2(ax, ay);
    } else {
        float a = 0.f;
        for (int i = s; i < e; i++) {
            a += csr_val[i] * feat[(size_t)csr_col[i] * D + lane];
        }
        if (RELU) a = a > 0.f ? a : 0.f;
        out[(size_t)row * D + lane] = a;
    }
}

// ---------------- launch ----------------

extern "C" void kernel_launch(void* const* d_in, const int* in_sizes, int n_in,
                              void* d_out, int out_size, void* d_ws, size_t ws_size,
                              hipStream_t stream) {
    const float* x    = (const float*)d_in[0];
    const float* adj  = (const float*)d_in[1];
    const float* w1   = (const float*)d_in[2];
    const float* w2   = (const float*)d_in[3];
    const int*   esrc = (const int*)d_in[4];
    const int*   edst = (const int*)d_in[5];
    float* out = (float*)d_out;

    const int N = N_NODES;
    const int E = N_EDGES;

    char* ws = (char*)d_ws;
    size_t off = 0;
    auto take = [&](size_t bytes) -> char* {
        char* p = ws + off;
        off = (off + bytes + 255) & ~(size_t)255;
        return p;
    };
    int*   deg     = (int*)take((size_t)N * 4);        // later reused as scatter cursor
    int*   row_ptr = (int*)take((size_t)(N + 1) * 4);
    int*   partial = (int*)take(128 * 4);
    int*   csr_col = (int*)take((size_t)E * 4);
    float* csr_val = (float*)take((size_t)E * 4);
    float* pre1    = (float*)take((size_t)N * HIDDEN * 4);  // reused for pre2
    float* h       = (float*)take((size_t)N * HIDDEN * 4);

    const int nb = (N + 1023) / 1024;  // 98 scan blocks

    // CSR build (rows = dst)
    zero_kernel<<<(N + 255) / 256, 256, 0, stream>>>(deg, N);
    hist_kernel<<<(E + 255) / 256, 256, 0, stream>>>(edst, deg, E);
    scan_reduce<<<nb, 256, 0, stream>>>(deg, partial, N);
    scan_partials<<<1, 128, 0, stream>>>(partial, nb);
    scan_final<<<nb, 256, 0, stream>>>(deg, partial, row_ptr, N, E);
    copy_kernel<<<(N + 255) / 256, 256, 0, stream>>>(row_ptr, deg, N);  // cursor = row_ptr
    scatter_kernel<<<(E + 255) / 256, 256, 0, stream>>>(esrc, edst, adj, deg, csr_col, csr_val, E);

    // Layer 1: pre1 = X@W1 ; h = relu(A @ pre1)
    gemm_kernel<IN_DIM, HIDDEN, 8><<<(N + 63) / 64, 256, 0, stream>>>(x, w1, pre1, N);
    spmm_kernel<HIDDEN, true><<<(N + 3) / 4, 256, 0, stream>>>(pre1, csr_col, csr_val, row_ptr, h, N);

    // Layer 2: pre2 = h@W2 (reuse pre1 buffer) ; out = A @ pre2
    gemm_kernel<HIDDEN, OUT_DIM, 4><<<(N + 63) / 64, 256, 0, stream>>>(h, w2, pre1, N);
    spmm_kernel<OUT_DIM, false><<<(N + 3) / 4, 256, 0, stream>>>(pre1, csr_col, csr_val, row_ptr, out, N);
}

// Round 2
// 1092.002 us; speedup vs baseline: 1.1702x; 1.1702x over previous
//
#include <hip/hip_runtime.h>

#define N_NODES 100000
#define N_EDGES 3200000
#define IN_DIM 256
#define HIDDEN 128
#define OUT_DIM 64

// ---------------- CSR build ----------------

__global__ void zero_kernel(int* __restrict__ p, int n) {
    int i = blockIdx.x * blockDim.x + threadIdx.x;
    if (i < n) p[i] = 0;
}

__global__ void hist_kernel(const int* __restrict__ dst, int* __restrict__ deg, int n) {
    int i = blockIdx.x * blockDim.x + threadIdx.x;
    if (i < n) atomicAdd(&deg[dst[i]], 1);
}

// chunk = 1024 elements per block (256 thr x 4)
__global__ void scan_reduce(const int* __restrict__ deg, int* __restrict__ partial, int n) {
    __shared__ int s[256];
    int b = blockIdx.x, tid = threadIdx.x;
    int base = b * 1024 + tid * 4;
    int sum = 0;
#pragma unroll
    for (int i = 0; i < 4; i++) {
        int idx = base + i;
        if (idx < n) sum += deg[idx];
    }
    s[tid] = sum;
    __syncthreads();
    for (int off = 128; off > 0; off >>= 1) {
        if (tid < off) s[tid] += s[tid + off];
        __syncthreads();
    }
    if (tid == 0) partial[b] = s[0];
}

__global__ void scan_partials(int* partial, int nb) {
    __shared__ int s[128];
    int tid = threadIdx.x;
    int v = (tid < nb) ? partial[tid] : 0;
    s[tid] = v;
    __syncthreads();
    for (int off = 1; off < 128; off <<= 1) {
        int t = 0;
        if (tid >= off) t = s[tid - off];
        __syncthreads();
        if (tid >= off) s[tid] += t;
        __syncthreads();
    }
    if (tid < nb) partial[tid] = s[tid] - v;  // exclusive prefix
}

// writes row_ptr AND the scatter cursor copy (folds old copy_kernel)
__global__ void scan_final(const int* __restrict__ deg, const int* __restrict__ partial,
                           int* __restrict__ row_ptr, int* __restrict__ cursor,
                           int n, int total) {
    __shared__ int s[256];
    int b = blockIdx.x, tid = threadIdx.x;
    int base = b * 1024 + tid * 4;
    int v[4];
#pragma unroll
    for (int i = 0; i < 4; i++) {
        int idx = base + i;
        v[i] = (idx < n) ? deg[idx] : 0;
    }
    int tsum = v[0] + v[1] + v[2] + v[3];
    s[tid] = tsum;
    __syncthreads();
    for (int off = 1; off < 256; off <<= 1) {
        int t = 0;
        if (tid >= off) t = s[tid - off];
        __syncthreads();
        if (tid >= off) s[tid] += t;
        __syncthreads();
    }
    int run = partial[b] + (s[tid] - tsum);
#pragma unroll
    for (int i = 0; i < 4; i++) {
        int idx = base + i;
        if (idx < n) { row_ptr[idx] = run; cursor[idx] = run; }
        run += v[i];
    }
    if (b == 0 && tid == 0) row_ptr[n] = total;
}

// CSR payload stored as interleaved (col, val_bits) pairs: one 8B store here,
// one 8B uniform load in spmm.
__global__ void scatter_kernel(const int* __restrict__ esrc, const int* __restrict__ edst,
                               const float* __restrict__ evals, int* __restrict__ cursor,
                               int2* __restrict__ csr_pair, int n) {
    int i = blockIdx.x * blockDim.x + threadIdx.x;
    if (i < n) {
        int d = edst[i];
        int p = atomicAdd(&cursor[d], 1);
        csr_pair[p] = make_int2(esrc[i], __float_as_int(evals[i]));
    }
}

// ---------------- dense GEMM (fp32 vector ALU; no fp32 MFMA on CDNA4) ----------------

template <int K, int BN, int TN>
__launch_bounds__(256)
__global__ void gemm_kernel(const float* __restrict__ A, const float* __restrict__ B,
                            float* __restrict__ C, int M) {
    constexpr int BM = 64, BK = 32;
    __shared__ float As[BK][BM + 1];
    __shared__ float Bs[BK][BN];
    int tid = threadIdx.x;
    int tm = tid >> 4, tn = tid & 15;
    int rowBase = blockIdx.x * BM;
    float acc[4][TN];
#pragma unroll
    for (int r = 0; r < 4; r++)
#pragma unroll
        for (int c = 0; c < TN; c++) acc[r][c] = 0.f;

    for (int k0 = 0; k0 < K; k0 += BK) {
#pragma unroll
        for (int i = 0; i < 8; i++) {
            int idx = tid + i * 256;
            int m = idx >> 5, kk = idx & 31;
            int row = rowBase + m;
            As[kk][m] = (row < M) ? A[(size_t)row * K + k0 + kk] : 0.f;
        }
#pragma unroll
        for (int i = 0; i < (BK * BN) / 256; i++) {
            int idx = tid + i * 256;
            int kk = idx / BN, nn = idx % BN;
            Bs[kk][nn] = B[(size_t)(k0 + kk) * BN + nn];
        }
        __syncthreads();
#pragma unroll
        for (int kk = 0; kk < BK; kk++) {
            float a[4], bb[TN];
#pragma unroll
            for (int r = 0; r < 4; r++) a[r] = As[kk][tm * 4 + r];
#pragma unroll
            for (int c = 0; c < TN; c++) bb[c] = Bs[kk][tn * TN + c];
#pragma unroll
            for (int r = 0; r < 4; r++)
#pragma unroll
                for (int c = 0; c < TN; c++) acc[r][c] += a[r] * bb[c];
        }
        __syncthreads();
    }
#pragma unroll
    for (int r = 0; r < 4; r++) {
        int row = rowBase + tm * 4 + r;
        if (row < M) {
#pragma unroll
            for (int c = 0; c < TN; c++) C[(size_t)row * BN + tn * TN + c] = acc[r][c];
        }
    }
}

// ---------------- SpMM: one wave per dst row, CSR pairs, unroll x4 ----------------
// 4 independent gathers in flight per wave to cover L2/L3 latency.

template <int D, bool RELU>
__launch_bounds__(256)
__global__ void spmm_kernel(const float* __restrict__ feat, const int2* __restrict__ csr_pair,
                            const int* __restrict__ row_ptr, float* __restrict__ out, int n) {
    int wid = threadIdx.x >> 6;
    int lane = threadIdx.x & 63;
    int row = blockIdx.x * 4 + wid;
    if (row >= n) return;
    int s = row_ptr[row], e = row_ptr[row + 1];

    if (D == 128) {
        float ax0 = 0.f, ay0 = 0.f, ax1 = 0.f, ay1 = 0.f;
        float ax2 = 0.f, ay2 = 0.f, ax3 = 0.f, ay3 = 0.f;
        int i = s;
        for (; i + 4 <= e; i += 4) {
            int2 p0 = csr_pair[i + 0];
            int2 p1 = csr_pair[i + 1];
            int2 p2 = csr_pair[i + 2];
            int2 p3 = csr_pair[i + 3];
            const float2 x0 = *reinterpret_cast<const float2*>(feat + (size_t)p0.x * 128 + lane * 2);
            const float2 x1 = *reinterpret_cast<const float2*>(feat + (size_t)p1.x * 128 + lane * 2);
            const float2 x2 = *reinterpret_cast<const float2*>(feat + (size_t)p2.x * 128 + lane * 2);
            const float2 x3 = *reinterpret_cast<const float2*>(feat + (size_t)p3.x * 128 + lane * 2);
            float v0 = __int_as_float(p0.y), v1 = __int_as_float(p1.y);
            float v2 = __int_as_float(p2.y), v3 = __int_as_float(p3.y);
            ax0 += v0 * x0.x; ay0 += v0 * x0.y;
            ax1 += v1 * x1.x; ay1 += v1 * x1.y;
            ax2 += v2 * x2.x; ay2 += v2 * x2.y;
            ax3 += v3 * x3.x; ay3 += v3 * x3.y;
        }
        for (; i < e; i++) {
            int2 p = csr_pair[i];
            const float2 xv = *reinterpret_cast<const float2*>(feat + (size_t)p.x * 128 + lane * 2);
            float v = __int_as_float(p.y);
            ax0 += v * xv.x; ay0 += v * xv.y;
        }
        float ax = (ax0 + ax1) + (ax2 + ax3);
        float ay = (ay0 + ay1) + (ay2 + ay3);
        if (RELU) {
            ax = ax > 0.f ? ax : 0.f;
            ay = ay > 0.f ? ay : 0.f;
        }
        *reinterpret_cast<float2*>(out + (size_t)row * 128 + lane * 2) = make_float2(ax, ay);
    } else {
        float a0 = 0.f, a1 = 0.f, a2 = 0.f, a3 = 0.f;
        int i = s;
        for (; i + 4 <= e; i += 4) {
            int2 p0 = csr_pair[i + 0];
            int2 p1 = csr_pair[i + 1];
            int2 p2 = csr_pair[i + 2];
            int2 p3 = csr_pair[i + 3];
            float x0 = feat[(size_t)p0.x * D + lane];
            float x1 = feat[(size_t)p1.x * D + lane];
            float x2 = feat[(size_t)p2.x * D + lane];
            float x3 = feat[(size_t)p3.x * D + lane];
            a0 += __int_as_float(p0.y) * x0;
            a1 += __int_as_float(p1.y) * x1;
            a2 += __int_as_float(p2.y) * x2;
            a3 += __int_as_float(p3.y) * x3;
        }
        for (; i < e; i++) {
            int2 p = csr_pair[i];
            a0 += __int_as_float(p.y) * feat[(size_t)p.x * D + lane];
        }
        float a = (a0 + a1) + (a2 + a3);
        if (RELU) a = a > 0.f ? a : 0.f;
        out[(size_t)row * D + lane] = a;
    }
}

// ---------------- launch ----------------

extern "C" void kernel_launch(void* const* d_in, const int* in_sizes, int n_in,
                              void* d_out, int out_size, void* d_ws, size_t ws_size,
                              hipStream_t stream) {
    const float* x    = (const float*)d_in[0];
    const float* adj  = (const float*)d_in[1];
    const float* w1   = (const float*)d_in[2];
    const float* w2   = (const float*)d_in[3];
    const int*   esrc = (const int*)d_in[4];
    const int*   edst = (const int*)d_in[5];
    float* out = (float*)d_out;

    const int N = N_NODES;
    const int E = N_EDGES;

    char* ws = (char*)d_ws;
    size_t off = 0;
    auto take = [&](size_t bytes) -> char* {
        char* p = ws + off;
        off = (off + bytes + 255) & ~(size_t)255;
        return p;
    };
    int*   deg      = (int*)take((size_t)N * 4);   // reused as scatter cursor
    int*   row_ptr  = (int*)take((size_t)(N + 1) * 4);
    int*   partial  = (int*)take(128 * 4);
    int2*  csr_pair = (int2*)take((size_t)E * 8);
    float* pre1     = (float*)take((size_t)N * HIDDEN * 4);  // reused for pre2
    float* h        = (float*)take((size_t)N * HIDDEN * 4);

    const int nb = (N + 1023) / 1024;  // 98 scan blocks

    // CSR build (rows = dst)
    zero_kernel<<<(N + 255) / 256, 256, 0, stream>>>(deg, N);
    hist_kernel<<<(E + 255) / 256, 256, 0, stream>>>(edst, deg, E);
    scan_reduce<<<nb, 256, 0, stream>>>(deg, partial, N);
    scan_partials<<<1, 128, 0, stream>>>(partial, nb);
    scan_final<<<nb, 256, 0, stream>>>(deg, partial, row_ptr, deg /*cursor*/, N, E);
    scatter_kernel<<<(E + 255) / 256, 256, 0, stream>>>(esrc, edst, adj, deg, csr_pair, E);

    // Layer 1: pre1 = X@W1 ; h = relu(A @ pre1)
    gemm_kernel<IN_DIM, HIDDEN, 8><<<(N + 63) / 64, 256, 0, stream>>>(x, w1, pre1, N);
    spmm_kernel<HIDDEN, true><<<(N + 3) / 4, 256, 0, stream>>>(pre1, csr_pair, row_ptr, h, N);

    // Layer 2: pre2 = h@W2 (reuse pre1 buffer) ; out = A @ pre2
    gemm_kernel<HIDDEN, OUT_DIM, 4><<<(N + 63) / 64, 256, 0, stream>>>(h, w2, pre1, N);
    spmm_kernel<OUT_DIM, false><<<(N + 3) / 4, 256, 0, stream>>>(pre1, csr_pair, row_ptr, out, N);
}